// Round 1
// baseline (604.900 us; speedup 1.0000x reference)
//
#include <hip/hip_runtime.h>

#define DEV_INLINE __device__ __forceinline__

static constexpr int KDIM = 128;

// ---------------------------------------------------------------- helpers
DEV_INLINE void fma4(float a, const float4& w, float4& c) {
    c.x = fmaf(a, w.x, c.x);
    c.y = fmaf(a, w.y, c.y);
    c.z = fmaf(a, w.z, c.z);
    c.w = fmaf(a, w.w, c.w);
}

// ---------------------------------------------------------------- degree / CSR build
__global__ void k_init(int* __restrict__ cnt, int N) {
    int i = blockIdx.x * 256 + threadIdx.x;
    if (i < N) cnt[i] = 0;
}

__global__ void k_count(const int* __restrict__ dst, int* __restrict__ cnt, int E) {
    int e = blockIdx.x * 256 + threadIdx.x;
    if (e < E) atomicAdd(&cnt[dst[e]], 1);
}

// 1024 elements per block, 256 threads x 4 elems. Local exclusive scan + block sum.
__global__ void k_scan1(const int* __restrict__ cnt, int* __restrict__ row_start,
                        int* __restrict__ bsums, int N) {
    __shared__ int sbuf[256];
    int t = threadIdx.x;
    int base = blockIdx.x * 1024 + t * 4;
    int v[4];
#pragma unroll
    for (int i = 0; i < 4; ++i) v[i] = (base + i < N) ? cnt[base + i] : 0;
    int T = v[0] + v[1] + v[2] + v[3];
    sbuf[t] = T;
    __syncthreads();
    for (int off = 1; off < 256; off <<= 1) {
        int add = (t >= off) ? sbuf[t - off] : 0;
        __syncthreads();
        sbuf[t] += add;
        __syncthreads();
    }
    int incl = sbuf[t];
    int run = incl - T;  // exclusive
#pragma unroll
    for (int i = 0; i < 4; ++i) {
        if (base + i < N) row_start[base + i] = run;
        run += v[i];
    }
    if (t == 255) bsums[blockIdx.x] = incl;
}

__global__ void k_scan2(int* __restrict__ bsums, int nb) {
    if (threadIdx.x == 0 && blockIdx.x == 0) {
        int run = 0;
        for (int i = 0; i < nb; ++i) { int v = bsums[i]; bsums[i] = run; run += v; }
    }
}

__global__ void k_scan3(int* __restrict__ row_start, int* __restrict__ cursor,
                        const int* __restrict__ bsums, const int* __restrict__ cnt,
                        float* __restrict__ dinv, int N) {
    int i = blockIdx.x * 256 + threadIdx.x;
    if (i < N) {
        int rs = row_start[i] + bsums[i >> 10];
        row_start[i] = rs;
        cursor[i] = rs;
        dinv[i] = rsqrtf((float)cnt[i] + 1.0f);  // +1 = self-loop
    }
}

__global__ void k_fill(const int* __restrict__ src, const int* __restrict__ dst,
                       int* __restrict__ cursor, int* __restrict__ csr_src, int E) {
    int e = blockIdx.x * 256 + threadIdx.x;
    if (e < E) {
        int d = dst[e];
        int pos = atomicAdd(&cursor[d], 1);
        csr_src[pos] = src[e];
    }
}

// ---------------------------------------------------------------- fp32 GEMM  H = act(A) @ W
// Epilogue: H[row]      = acc                 (raw, gathered later)
//           OutInit[row]= dinv[row]^2 * acc + bias   (self-loop term + bias pre-added)
template <int NOUT, bool RELU_IN>
__global__ __launch_bounds__(256, 2) void k_gemm(
    const float* __restrict__ A, const float* __restrict__ W,
    const float* __restrict__ bias, const float* __restrict__ dinv,
    float* __restrict__ H, float* __restrict__ OutInit, int N) {
    constexpr int COLG = NOUT / 4;        // float4 col groups: 32 or 16
    constexpr int ROWG = 256 / COLG;      // 8 or 16
    constexpr int TM = ROWG * 4;          // 32 or 64 rows per block
    constexpr int ASTR = (NOUT == 64) ? (KDIM + 4) : KDIM;   // pad to break bank aliasing
    constexpr int WSTR = (NOUT == 64) ? (NOUT + 4) : NOUT;
    __shared__ float As[TM * ASTR];
    __shared__ float Ws[KDIM * WSTR];
    const int tid = threadIdx.x;
    const int tc = tid % COLG;
    const int tr = tid / COLG;
    const int row0 = blockIdx.x * TM;

    // stage W (row-major [K][NOUT]) into LDS
    for (int i = tid; i < KDIM * NOUT / 4; i += 256) {
        int k = i / COLG;
        int c4 = i - k * COLG;
        float4 v = reinterpret_cast<const float4*>(W)[i];
        *reinterpret_cast<float4*>(&Ws[k * WSTR + c4 * 4]) = v;
    }
    // stage A tile [TM][128]
    for (int i = tid; i < TM * KDIM / 4; i += 256) {
        int r = i >> 5;   // / 32  (KDIM/4 == 32)
        int c4 = i & 31;
        int grow = row0 + r;
        float4 v = make_float4(0.f, 0.f, 0.f, 0.f);
        if (grow < N) v = reinterpret_cast<const float4*>(A)[grow * 32 + c4];
        if (RELU_IN) {
            v.x = fmaxf(v.x, 0.f); v.y = fmaxf(v.y, 0.f);
            v.z = fmaxf(v.z, 0.f); v.w = fmaxf(v.w, 0.f);
        }
        *reinterpret_cast<float4*>(&As[r * ASTR + c4 * 4]) = v;
    }
    __syncthreads();

    float4 acc[4];
#pragma unroll
    for (int r = 0; r < 4; ++r) acc[r] = make_float4(0.f, 0.f, 0.f, 0.f);

    const float4* As4 = reinterpret_cast<const float4*>(As);
    const float4* Ws4 = reinterpret_cast<const float4*>(Ws);
#pragma unroll 4
    for (int kk = 0; kk < KDIM / 4; ++kk) {
        float4 av[4], wv[4];
#pragma unroll
        for (int r = 0; r < 4; ++r) av[r] = As4[(tr * 4 + r) * (ASTR / 4) + kk];
#pragma unroll
        for (int j = 0; j < 4; ++j) wv[j] = Ws4[(kk * 4 + j) * (WSTR / 4) + tc];
#pragma unroll
        for (int r = 0; r < 4; ++r) {
            fma4(av[r].x, wv[0], acc[r]);
            fma4(av[r].y, wv[1], acc[r]);
            fma4(av[r].z, wv[2], acc[r]);
            fma4(av[r].w, wv[3], acc[r]);
        }
    }

    float4 bv = reinterpret_cast<const float4*>(bias)[tc];
#pragma unroll
    for (int r = 0; r < 4; ++r) {
        int grow = row0 + tr * 4 + r;
        if (grow < N) {
            float di = dinv[grow];
            float d2 = di * di;
            reinterpret_cast<float4*>(H)[grow * COLG + tc] = acc[r];
            float4 z;
            z.x = fmaf(d2, acc[r].x, bv.x);
            z.y = fmaf(d2, acc[r].y, bv.y);
            z.z = fmaf(d2, acc[r].z, bv.z);
            z.w = fmaf(d2, acc[r].w, bv.w);
            reinterpret_cast<float4*>(OutInit)[grow * COLG + tc] = z;
        }
    }
}

// ---------------------------------------------------------------- CSR gather-aggregate
// Acc[node] += sum_{j in in-edges(node)} dinv[node]*dinv[src_j] * Hsrc[src_j]
// CPG = float4 lanes per node (32 -> 128 ch, 16 -> 64 ch). One thread owns one float4 slot.
template <int CPG>
__global__ void k_gather(const int* __restrict__ row_start, const int* __restrict__ row_end,
                         const int* __restrict__ csr_src, const float* __restrict__ dinv,
                         const float* __restrict__ Hsrc, float* __restrict__ Acc, int N) {
    const int lane = threadIdx.x % CPG;
    const int node = blockIdx.x * (256 / CPG) + threadIdx.x / CPG;
    if (node >= N) return;
    const int s0 = row_start[node];
    const int s1 = row_end[node];
    const float dn = dinv[node];
    const float4* H4 = reinterpret_cast<const float4*>(Hsrc);
    float4 acc = make_float4(0.f, 0.f, 0.f, 0.f);
    for (int j = s0; j < s1; ++j) {
        int s = csr_src[j];              // uniform across the CPG lanes -> broadcast load
        float w = dn * dinv[s];
        float4 h = H4[(size_t)s * CPG + lane];
        fma4(w, h, acc);
    }
    float4* O4 = reinterpret_cast<float4*>(Acc);
    float4 o = O4[(size_t)node * CPG + lane];
    o.x += acc.x; o.y += acc.y; o.z += acc.z; o.w += acc.w;
    O4[(size_t)node * CPG + lane] = o;
}

// ---------------------------------------------------------------- launch
extern "C" void kernel_launch(void* const* d_in, const int* in_sizes, int n_in,
                              void* d_out, int out_size, void* d_ws, size_t ws_size,
                              hipStream_t stream) {
    const float* x  = (const float*)d_in[0];
    const int*   ei = (const int*)d_in[1];
    const float* W1 = (const float*)d_in[2];
    const float* b1 = (const float*)d_in[3];
    const float* W2 = (const float*)d_in[4];
    const float* b2 = (const float*)d_in[5];
    float* out = (float*)d_out;

    const int N = in_sizes[0] / 128;
    const int E = in_sizes[1] / 2;
    const int* src = ei;       // edge_index[0]
    const int* dst = ei + E;   // edge_index[1]

    char* ws = (char*)d_ws;
    size_t off = 0;
    auto alloc = [&](size_t bytes) -> char* {
        char* p = ws + off;
        off += (bytes + 255) & ~size_t(255);
        return p;
    };
    int*   cnt       = (int*)alloc((size_t)N * 4);
    int*   row_start = (int*)alloc((size_t)N * 4);
    int*   cursor    = (int*)alloc((size_t)N * 4);
    float* dinv      = (float*)alloc((size_t)N * 4);
    int*   bsums     = (int*)alloc(4096);
    int*   csr_src   = (int*)alloc((size_t)E * 4);
    float* h         = (float*)alloc((size_t)N * 128 * 4);  // h1, reused as h2
    float* zp        = (float*)alloc((size_t)N * 128 * 4);  // z_pre (conv1 accumulator)
    (void)ws_size; (void)n_in; (void)out_size;

    const int nb = (N + 1023) / 1024;

    hipLaunchKernelGGL(k_init,  dim3((N + 255) / 256), dim3(256), 0, stream, cnt, N);
    hipLaunchKernelGGL(k_count, dim3((E + 255) / 256), dim3(256), 0, stream, dst, cnt, E);
    hipLaunchKernelGGL(k_scan1, dim3(nb), dim3(256), 0, stream, cnt, row_start, bsums, N);
    hipLaunchKernelGGL(k_scan2, dim3(1), dim3(64), 0, stream, bsums, nb);
    hipLaunchKernelGGL(k_scan3, dim3((N + 255) / 256), dim3(256), 0, stream,
                       row_start, cursor, bsums, cnt, dinv, N);
    hipLaunchKernelGGL(k_fill,  dim3((E + 255) / 256), dim3(256), 0, stream,
                       src, dst, cursor, csr_src, E);

    // conv1: h = x@W1 ; zp = dinv^2*h + b1 ; zp += gathered msgs
    hipLaunchKernelGGL((k_gemm<128, false>), dim3((N + 31) / 32), dim3(256), 0, stream,
                       x, W1, b1, dinv, h, zp, N);
    hipLaunchKernelGGL((k_gather<32>), dim3((N + 7) / 8), dim3(256), 0, stream,
                       row_start, cursor, csr_src, dinv, h, zp, N);

    // conv2: h2 = relu(zp)@W2 ; out = dinv^2*h2 + b2 ; out += gathered msgs
    hipLaunchKernelGGL((k_gemm<64, true>), dim3((N + 63) / 64), dim3(256), 0, stream,
                       zp, W2, b2, dinv, h, out, N);
    hipLaunchKernelGGL((k_gather<16>), dim3((N + 15) / 16), dim3(256), 0, stream,
                       row_start, cursor, csr_src, dinv, h, out, N);
}

// Round 2
// 502.287 us; speedup vs baseline: 1.2043x; 1.2043x over previous
//
#include <hip/hip_runtime.h>

#define DEV_INLINE __device__ __forceinline__

static constexpr int KDIM = 128;

// ---------------------------------------------------------------- helpers
DEV_INLINE void fma4(float a, const float4& w, float4& c) {
    c.x = fmaf(a, w.x, c.x);
    c.y = fmaf(a, w.y, c.y);
    c.z = fmaf(a, w.z, c.z);
    c.w = fmaf(a, w.w, c.w);
}

DEV_INLINE float bf2f_lo(unsigned int u) {   // low 16 bits -> float
    union { unsigned int u; float f; } c; c.u = u << 16; return c.f;
}
DEV_INLINE float bf2f_hi(unsigned int u) {   // high 16 bits -> float
    union { unsigned int u; float f; } c; c.u = u & 0xFFFF0000u; return c.f;
}
DEV_INLINE unsigned int f2bf(float f) {      // round-to-nearest-even
    union { float f; unsigned int u; } c; c.f = f;
    return (c.u + 0x7FFFu + ((c.u >> 16) & 1u)) >> 16;
}

DEV_INLINE void fma8(float w, const uint4& h, float* acc) {
    acc[0] = fmaf(w, bf2f_lo(h.x), acc[0]);
    acc[1] = fmaf(w, bf2f_hi(h.x), acc[1]);
    acc[2] = fmaf(w, bf2f_lo(h.y), acc[2]);
    acc[3] = fmaf(w, bf2f_hi(h.y), acc[3]);
    acc[4] = fmaf(w, bf2f_lo(h.z), acc[4]);
    acc[5] = fmaf(w, bf2f_hi(h.z), acc[5]);
    acc[6] = fmaf(w, bf2f_lo(h.w), acc[6]);
    acc[7] = fmaf(w, bf2f_hi(h.w), acc[7]);
}

// ---------------------------------------------------------------- degree / CSR build
__global__ void k_init(int* __restrict__ cnt, int N) {
    int i = blockIdx.x * 256 + threadIdx.x;
    if (i < N) cnt[i] = 0;
}

__global__ void k_count(const int* __restrict__ dst, int* __restrict__ cnt, int E) {
    int e = blockIdx.x * 256 + threadIdx.x;
    if (e < E) atomicAdd(&cnt[dst[e]], 1);
}

// 1024 elements per block, 256 threads x 4 elems. Local exclusive scan + block sum.
__global__ void k_scan1(const int* __restrict__ cnt, int* __restrict__ row_start,
                        int* __restrict__ bsums, int N) {
    __shared__ int sbuf[256];
    int t = threadIdx.x;
    int base = blockIdx.x * 1024 + t * 4;
    int v[4];
#pragma unroll
    for (int i = 0; i < 4; ++i) v[i] = (base + i < N) ? cnt[base + i] : 0;
    int T = v[0] + v[1] + v[2] + v[3];
    sbuf[t] = T;
    __syncthreads();
    for (int off = 1; off < 256; off <<= 1) {
        int add = (t >= off) ? sbuf[t - off] : 0;
        __syncthreads();
        sbuf[t] += add;
        __syncthreads();
    }
    int incl = sbuf[t];
    int run = incl - T;  // exclusive
#pragma unroll
    for (int i = 0; i < 4; ++i) {
        if (base + i < N) row_start[base + i] = run;
        run += v[i];
    }
    if (t == 255) bsums[blockIdx.x] = incl;
}

// parallel single-block exclusive scan of block sums (nb <= 256)
__global__ void k_scan2(int* __restrict__ bsums, int nb) {
    __shared__ int sbuf[256];
    int t = threadIdx.x;
    int v = (t < nb) ? bsums[t] : 0;
    sbuf[t] = v;
    __syncthreads();
    for (int off = 1; off < 256; off <<= 1) {
        int add = (t >= off) ? sbuf[t - off] : 0;
        __syncthreads();
        sbuf[t] += add;
        __syncthreads();
    }
    if (t < nb) bsums[t] = sbuf[t] - v;  // exclusive
}

__global__ void k_scan3(int* __restrict__ row_start, int* __restrict__ cursor,
                        const int* __restrict__ bsums, const int* __restrict__ cnt,
                        float* __restrict__ dinv, int N) {
    int i = blockIdx.x * 256 + threadIdx.x;
    if (i < N) {
        int rs = row_start[i] + bsums[i >> 10];
        row_start[i] = rs;
        cursor[i] = rs;
        dinv[i] = rsqrtf((float)cnt[i] + 1.0f);  // +1 = self-loop
    }
}

__global__ void k_fill(const int* __restrict__ src, const int* __restrict__ dst,
                       int* __restrict__ cursor, int* __restrict__ csr_src, int E) {
    int e = blockIdx.x * 256 + threadIdx.x;
    if (e < E) {
        int d = dst[e];
        int pos = atomicAdd(&cursor[d], 1);
        csr_src[pos] = src[e];
    }
}

// ---------------------------------------------------------------- fp32 GEMM  H = act(A) @ W
// Epilogue: Hs[row]     = bf16(dinv[row] * acc)          (pre-scaled, gathered later)
//           OutInit[row]= dinv[row]^2 * acc + bias       (self-loop term + bias, fp32)
template <int NOUT, bool RELU_IN>
__global__ __launch_bounds__(256, 2) void k_gemm(
    const float* __restrict__ A, const float* __restrict__ W,
    const float* __restrict__ bias, const float* __restrict__ dinv,
    unsigned short* __restrict__ Hs, float* __restrict__ OutInit, int N) {
    constexpr int COLG = NOUT / 4;        // float4 col groups: 32 or 16
    constexpr int ROWG = 256 / COLG;      // 8 or 16
    constexpr int TM = ROWG * 4;          // 32 or 64 rows per block
    constexpr int ASTR = (NOUT == 64) ? (KDIM + 4) : KDIM;
    constexpr int WSTR = (NOUT == 64) ? (NOUT + 4) : NOUT;
    __shared__ float As[TM * ASTR];
    __shared__ float Ws[KDIM * WSTR];
    const int tid = threadIdx.x;
    const int tc = tid % COLG;
    const int tr = tid / COLG;
    const int row0 = blockIdx.x * TM;

    for (int i = tid; i < KDIM * NOUT / 4; i += 256) {
        int k = i / COLG;
        int c4 = i - k * COLG;
        float4 v = reinterpret_cast<const float4*>(W)[i];
        *reinterpret_cast<float4*>(&Ws[k * WSTR + c4 * 4]) = v;
    }
    for (int i = tid; i < TM * KDIM / 4; i += 256) {
        int r = i >> 5;   // / 32  (KDIM/4 == 32)
        int c4 = i & 31;
        int grow = row0 + r;
        float4 v = make_float4(0.f, 0.f, 0.f, 0.f);
        if (grow < N) v = reinterpret_cast<const float4*>(A)[grow * 32 + c4];
        if (RELU_IN) {
            v.x = fmaxf(v.x, 0.f); v.y = fmaxf(v.y, 0.f);
            v.z = fmaxf(v.z, 0.f); v.w = fmaxf(v.w, 0.f);
        }
        *reinterpret_cast<float4*>(&As[r * ASTR + c4 * 4]) = v;
    }
    __syncthreads();

    float4 acc[4];
#pragma unroll
    for (int r = 0; r < 4; ++r) acc[r] = make_float4(0.f, 0.f, 0.f, 0.f);

    const float4* As4 = reinterpret_cast<const float4*>(As);
    const float4* Ws4 = reinterpret_cast<const float4*>(Ws);
#pragma unroll 4
    for (int kk = 0; kk < KDIM / 4; ++kk) {
        float4 av[4], wv[4];
#pragma unroll
        for (int r = 0; r < 4; ++r) av[r] = As4[(tr * 4 + r) * (ASTR / 4) + kk];
#pragma unroll
        for (int j = 0; j < 4; ++j) wv[j] = Ws4[(kk * 4 + j) * (WSTR / 4) + tc];
#pragma unroll
        for (int r = 0; r < 4; ++r) {
            fma4(av[r].x, wv[0], acc[r]);
            fma4(av[r].y, wv[1], acc[r]);
            fma4(av[r].z, wv[2], acc[r]);
            fma4(av[r].w, wv[3], acc[r]);
        }
    }

    float4 bv = reinterpret_cast<const float4*>(bias)[tc];
#pragma unroll
    for (int r = 0; r < 4; ++r) {
        int grow = row0 + tr * 4 + r;
        if (grow < N) {
            float di = dinv[grow];
            float d2 = di * di;
            // pre-scaled bf16 copy for the gather
            uint2 hb;
            hb.x = f2bf(di * acc[r].x) | (f2bf(di * acc[r].y) << 16);
            hb.y = f2bf(di * acc[r].z) | (f2bf(di * acc[r].w) << 16);
            *reinterpret_cast<uint2*>(&Hs[(size_t)grow * NOUT + tc * 4]) = hb;
            // self-loop + bias in fp32
            float4 z;
            z.x = fmaf(d2, acc[r].x, bv.x);
            z.y = fmaf(d2, acc[r].y, bv.y);
            z.z = fmaf(d2, acc[r].z, bv.z);
            z.w = fmaf(d2, acc[r].w, bv.w);
            reinterpret_cast<float4*>(OutInit)[grow * COLG + tc] = z;
        }
    }
}

// ---------------------------------------------------------------- CSR gather-aggregate
// Acc[node] += dinv[node] * sum_j Hs[src_j]     (Hs pre-scaled by dinv[src])
// LPG lanes per node, each lane owns 8 channels (uint4 = 8 bf16).
template <int NOUT>
__global__ void k_gather(const int* __restrict__ row_start, const int* __restrict__ row_end,
                         const int* __restrict__ csr_src,
                         const float* __restrict__ dinv,
                         const unsigned short* __restrict__ Hs,
                         float* __restrict__ Acc, int N) {
    constexpr int LPG = NOUT / 8;
    const int lane = threadIdx.x % LPG;
    const int node = blockIdx.x * (256 / LPG) + threadIdx.x / LPG;
    if (node >= N) return;
    const int s0 = row_start[node];
    const int s1 = row_end[node];
    if (s0 == s1) return;
    const float dn = dinv[node];
    const uint4* H8 = reinterpret_cast<const uint4*>(Hs);
    float acc[8];
#pragma unroll
    for (int i = 0; i < 8; ++i) acc[i] = 0.f;

    int j = s0;
    for (; j + 2 <= s1; j += 2) {
        int sa = csr_src[j];
        int sb = csr_src[j + 1];
        uint4 ha = H8[(size_t)sa * LPG + lane];
        uint4 hb = H8[(size_t)sb * LPG + lane];
        fma8(dn, ha, acc);
        fma8(dn, hb, acc);
    }
    if (j < s1) {
        int sa = csr_src[j];
        uint4 ha = H8[(size_t)sa * LPG + lane];
        fma8(dn, ha, acc);
    }

    float4* O4 = reinterpret_cast<float4*>(Acc + (size_t)node * NOUT + lane * 8);
    float4 o0 = O4[0], o1 = O4[1];
    o0.x += acc[0]; o0.y += acc[1]; o0.z += acc[2]; o0.w += acc[3];
    o1.x += acc[4]; o1.y += acc[5]; o1.z += acc[6]; o1.w += acc[7];
    O4[0] = o0; O4[1] = o1;
}

// ---------------------------------------------------------------- launch
extern "C" void kernel_launch(void* const* d_in, const int* in_sizes, int n_in,
                              void* d_out, int out_size, void* d_ws, size_t ws_size,
                              hipStream_t stream) {
    const float* x  = (const float*)d_in[0];
    const int*   ei = (const int*)d_in[1];
    const float* W1 = (const float*)d_in[2];
    const float* b1 = (const float*)d_in[3];
    const float* W2 = (const float*)d_in[4];
    const float* b2 = (const float*)d_in[5];
    float* out = (float*)d_out;

    const int N = in_sizes[0] / 128;
    const int E = in_sizes[1] / 2;
    const int* src = ei;       // edge_index[0]
    const int* dst = ei + E;   // edge_index[1]

    char* ws = (char*)d_ws;
    size_t off = 0;
    auto alloc = [&](size_t bytes) -> char* {
        char* p = ws + off;
        off += (bytes + 255) & ~size_t(255);
        return p;
    };
    int*            cnt       = (int*)alloc((size_t)N * 4);
    int*            row_start = (int*)alloc((size_t)N * 4);
    int*            cursor    = (int*)alloc((size_t)N * 4);
    float*          dinv      = (float*)alloc((size_t)N * 4);
    int*            bsums     = (int*)alloc(4096);
    int*            csr_src   = (int*)alloc((size_t)E * 4);
    unsigned short* hs        = (unsigned short*)alloc((size_t)N * 128 * 2);  // bf16 h (conv1/conv2)
    float*          zp        = (float*)alloc((size_t)N * 128 * 4);           // conv1 accumulator
    (void)ws_size; (void)n_in; (void)out_size;

    const int nb = (N + 1023) / 1024;

    hipLaunchKernelGGL(k_init,  dim3((N + 255) / 256), dim3(256), 0, stream, cnt, N);
    hipLaunchKernelGGL(k_count, dim3((E + 255) / 256), dim3(256), 0, stream, dst, cnt, E);
    hipLaunchKernelGGL(k_scan1, dim3(nb), dim3(256), 0, stream, cnt, row_start, bsums, N);
    hipLaunchKernelGGL(k_scan2, dim3(1), dim3(256), 0, stream, bsums, nb);
    hipLaunchKernelGGL(k_scan3, dim3((N + 255) / 256), dim3(256), 0, stream,
                       row_start, cursor, bsums, cnt, dinv, N);
    hipLaunchKernelGGL(k_fill,  dim3((E + 255) / 256), dim3(256), 0, stream,
                       src, dst, cursor, csr_src, E);

    // conv1: h = x@W1 ; zp = dinv^2*h + b1 ; zp += gathered msgs
    hipLaunchKernelGGL((k_gemm<128, false>), dim3((N + 31) / 32), dim3(256), 0, stream,
                       x, W1, b1, dinv, hs, zp, N);
    hipLaunchKernelGGL((k_gather<128>), dim3((N + 15) / 16), dim3(256), 0, stream,
                       row_start, cursor, csr_src, dinv, hs, zp, N);

    // conv2: h2 = relu(zp)@W2 ; out = dinv^2*h2 + b2 ; out += gathered msgs
    hipLaunchKernelGGL((k_gemm<64, true>), dim3((N + 63) / 64), dim3(256), 0, stream,
                       zp, W2, b2, dinv, hs, out, N);
    hipLaunchKernelGGL((k_gather<64>), dim3((N + 31) / 32), dim3(256), 0, stream,
                       row_start, cursor, csr_src, dinv, hs, out, N);
}

// Round 3
// 363.120 us; speedup vs baseline: 1.6658x; 1.3833x over previous
//
#include <hip/hip_runtime.h>

#define DEV_INLINE __device__ __forceinline__

static constexpr int KDIM = 128;
static constexpr int BUCKET_SHIFT = 8;           // 256 nodes per bucket
static constexpr int BUCKET_NODES = 1 << BUCKET_SHIFT;
static constexpr int CAP = 6144;                 // max edges per bucket (avg ~4096)
static constexpr int MAXNB = 512;                // max buckets supported

// ---------------------------------------------------------------- helpers
DEV_INLINE void fma4(float a, const float4& w, float4& c) {
    c.x = fmaf(a, w.x, c.x);
    c.y = fmaf(a, w.y, c.y);
    c.z = fmaf(a, w.z, c.z);
    c.w = fmaf(a, w.w, c.w);
}

DEV_INLINE float bf2f_lo(unsigned int u) {
    union { unsigned int u; float f; } c; c.u = u << 16; return c.f;
}
DEV_INLINE float bf2f_hi(unsigned int u) {
    union { unsigned int u; float f; } c; c.u = u & 0xFFFF0000u; return c.f;
}
DEV_INLINE unsigned int f2bf(float f) {      // round-to-nearest-even
    union { float f; unsigned int u; } c; c.f = f;
    return (c.u + 0x7FFFu + ((c.u >> 16) & 1u)) >> 16;
}

DEV_INLINE void fma8(float w, const uint4& h, float* acc) {
    acc[0] = fmaf(w, bf2f_lo(h.x), acc[0]);
    acc[1] = fmaf(w, bf2f_hi(h.x), acc[1]);
    acc[2] = fmaf(w, bf2f_lo(h.y), acc[2]);
    acc[3] = fmaf(w, bf2f_hi(h.y), acc[3]);
    acc[4] = fmaf(w, bf2f_lo(h.z), acc[4]);
    acc[5] = fmaf(w, bf2f_hi(h.z), acc[5]);
    acc[6] = fmaf(w, bf2f_lo(h.w), acc[6]);
    acc[7] = fmaf(w, bf2f_hi(h.w), acc[7]);
}

// ---------------------------------------------------------------- bucketed CSR build
__global__ void k_zero(int* __restrict__ bucket_cursor, int nb) {
    int i = blockIdx.x * 256 + threadIdx.x;
    if (i < nb) bucket_cursor[i] = 0;
}

// Block-local multisplit: LDS histogram -> one global atomic per (block,bucket)
// -> clustered record writes. Record = src | (dst&255)<<24.
template <int EPT>
__global__ __launch_bounds__(256) void k_bin(
    const int* __restrict__ src, const int* __restrict__ dst,
    int* __restrict__ bucket_cursor, unsigned int* __restrict__ rec,
    int E, int NB) {
    __shared__ int hist[MAXNB];
    __shared__ int base[MAXNB];
    const int t = threadIdx.x;
    for (int i = t; i < NB; i += 256) hist[i] = 0;
    __syncthreads();

    const int e0 = blockIdx.x * (256 * EPT);
    int d[EPT], s[EPT];
#pragma unroll
    for (int i = 0; i < EPT; ++i) {
        int e = e0 + i * 256 + t;
        d[i] = (e < E) ? dst[e] : -1;
        s[i] = (e < E) ? src[e] : 0;
    }
#pragma unroll
    for (int i = 0; i < EPT; ++i)
        if (d[i] >= 0) atomicAdd(&hist[d[i] >> BUCKET_SHIFT], 1);
    __syncthreads();

    for (int i = t; i < NB; i += 256) {
        int h = hist[i];
        base[i] = (h > 0) ? atomicAdd(&bucket_cursor[i], h) : 0;
        hist[i] = 0;   // reuse as local rank cursor
    }
    __syncthreads();

#pragma unroll
    for (int i = 0; i < EPT; ++i) {
        if (d[i] >= 0) {
            int b = d[i] >> BUCKET_SHIFT;
            int r = atomicAdd(&hist[b], 1);
            unsigned int p = (unsigned int)s[i] |
                             ((unsigned int)(d[i] & (BUCKET_NODES - 1)) << 24);
            rec[(size_t)b * CAP + base[b] + r] = p;
        }
    }
}

// One block per bucket: LDS degree hist -> dinv + row_start/row_end; LDS scan;
// LDS-atomic rank -> csr_src fill (bucket region is L2-resident).
__global__ __launch_bounds__(256) void k_degcsr(
    const int* __restrict__ bucket_cursor, const unsigned int* __restrict__ rec,
    int* __restrict__ csr_src, int* __restrict__ row_start, int* __restrict__ row_end,
    float* __restrict__ dinv, int N) {
    __shared__ int cnt[BUCKET_NODES];
    __shared__ int rstart[BUCKET_NODES];
    __shared__ int sc[BUCKET_NODES];
    const int b = blockIdx.x;
    const int t = threadIdx.x;
    const int node0 = b << BUCKET_SHIFT;
    const int ne = bucket_cursor[b];
    cnt[t] = 0;
    __syncthreads();

    const unsigned int* r0 = rec + (size_t)b * CAP;
    for (int j = t; j < ne; j += 256) atomicAdd(&cnt[r0[j] >> 24], 1);
    __syncthreads();

    int v = cnt[t];
    sc[t] = v;
    __syncthreads();
    for (int off = 1; off < 256; off <<= 1) {
        int add = (t >= off) ? sc[t - off] : 0;
        __syncthreads();
        sc[t] += add;
        __syncthreads();
    }
    int rs = sc[t] - v;  // exclusive
    rstart[t] = rs;
    if (node0 + t < N) {
        row_start[node0 + t] = b * CAP + rs;
        row_end[node0 + t]   = b * CAP + rs + v;
        dinv[node0 + t] = rsqrtf((float)v + 1.0f);  // +1 self-loop
    }
    cnt[t] = 0;  // reuse as rank cursor
    __syncthreads();

    for (int j = t; j < ne; j += 256) {
        unsigned int p = r0[j];
        int loc = p >> 24;
        int rk = atomicAdd(&cnt[loc], 1);
        csr_src[(size_t)b * CAP + rstart[loc] + rk] = (int)(p & 0x00FFFFFFu);
    }
}

// ---------------------------------------------------------------- fp32 GEMM  H = act(A) @ W
// Epilogue: Hs[row]     = bf16(dinv[row] * acc)          (pre-scaled, gathered later)
//           OutInit[row]= dinv[row]^2 * acc + bias       (self-loop term + bias, fp32)
template <int NOUT, bool RELU_IN>
__global__ __launch_bounds__(256, 2) void k_gemm(
    const float* __restrict__ A, const float* __restrict__ W,
    const float* __restrict__ bias, const float* __restrict__ dinv,
    unsigned short* __restrict__ Hs, float* __restrict__ OutInit, int N) {
    constexpr int COLG = NOUT / 4;        // float4 col groups: 32 or 16
    constexpr int ROWG = 256 / COLG;      // 8 or 16
    constexpr int TM = ROWG * 4;          // 32 or 64 rows per block
    constexpr int ASTR = (NOUT == 64) ? (KDIM + 4) : KDIM;
    constexpr int WSTR = (NOUT == 64) ? (NOUT + 4) : NOUT;
    __shared__ float As[TM * ASTR];
    __shared__ float Ws[KDIM * WSTR];
    const int tid = threadIdx.x;
    const int tc = tid % COLG;
    const int tr = tid / COLG;
    const int row0 = blockIdx.x * TM;

    for (int i = tid; i < KDIM * NOUT / 4; i += 256) {
        int k = i / COLG;
        int c4 = i - k * COLG;
        float4 v = reinterpret_cast<const float4*>(W)[i];
        *reinterpret_cast<float4*>(&Ws[k * WSTR + c4 * 4]) = v;
    }
    for (int i = tid; i < TM * KDIM / 4; i += 256) {
        int r = i >> 5;   // / 32  (KDIM/4 == 32)
        int c4 = i & 31;
        int grow = row0 + r;
        float4 v = make_float4(0.f, 0.f, 0.f, 0.f);
        if (grow < N) v = reinterpret_cast<const float4*>(A)[grow * 32 + c4];
        if (RELU_IN) {
            v.x = fmaxf(v.x, 0.f); v.y = fmaxf(v.y, 0.f);
            v.z = fmaxf(v.z, 0.f); v.w = fmaxf(v.w, 0.f);
        }
        *reinterpret_cast<float4*>(&As[r * ASTR + c4 * 4]) = v;
    }
    __syncthreads();

    float4 acc[4];
#pragma unroll
    for (int r = 0; r < 4; ++r) acc[r] = make_float4(0.f, 0.f, 0.f, 0.f);

    const float4* As4 = reinterpret_cast<const float4*>(As);
    const float4* Ws4 = reinterpret_cast<const float4*>(Ws);
#pragma unroll 4
    for (int kk = 0; kk < KDIM / 4; ++kk) {
        float4 av[4], wv[4];
#pragma unroll
        for (int r = 0; r < 4; ++r) av[r] = As4[(tr * 4 + r) * (ASTR / 4) + kk];
#pragma unroll
        for (int j = 0; j < 4; ++j) wv[j] = Ws4[(kk * 4 + j) * (WSTR / 4) + tc];
#pragma unroll
        for (int r = 0; r < 4; ++r) {
            fma4(av[r].x, wv[0], acc[r]);
            fma4(av[r].y, wv[1], acc[r]);
            fma4(av[r].z, wv[2], acc[r]);
            fma4(av[r].w, wv[3], acc[r]);
        }
    }

    float4 bv = reinterpret_cast<const float4*>(bias)[tc];
#pragma unroll
    for (int r = 0; r < 4; ++r) {
        int grow = row0 + tr * 4 + r;
        if (grow < N) {
            float di = dinv[grow];
            float d2 = di * di;
            uint2 hb;
            hb.x = f2bf(di * acc[r].x) | (f2bf(di * acc[r].y) << 16);
            hb.y = f2bf(di * acc[r].z) | (f2bf(di * acc[r].w) << 16);
            *reinterpret_cast<uint2*>(&Hs[(size_t)grow * NOUT + tc * 4]) = hb;
            float4 z;
            z.x = fmaf(d2, acc[r].x, bv.x);
            z.y = fmaf(d2, acc[r].y, bv.y);
            z.z = fmaf(d2, acc[r].z, bv.z);
            z.w = fmaf(d2, acc[r].w, bv.w);
            reinterpret_cast<float4*>(OutInit)[grow * COLG + tc] = z;
        }
    }
}

// ---------------------------------------------------------------- CSR gather-aggregate
// Acc[node] += dinv[node] * sum_j Hs[src_j]     (Hs pre-scaled by dinv[src])
template <int NOUT>
__global__ void k_gather(const int* __restrict__ row_start, const int* __restrict__ row_end,
                         const int* __restrict__ csr_src,
                         const float* __restrict__ dinv,
                         const unsigned short* __restrict__ Hs,
                         float* __restrict__ Acc, int N) {
    constexpr int LPG = NOUT / 8;
    const int lane = threadIdx.x % LPG;
    const int node = blockIdx.x * (256 / LPG) + threadIdx.x / LPG;
    if (node >= N) return;
    const int s0 = row_start[node];
    const int s1 = row_end[node];
    if (s0 == s1) return;
    const float dn = dinv[node];
    const uint4* H8 = reinterpret_cast<const uint4*>(Hs);
    float acc[8];
#pragma unroll
    for (int i = 0; i < 8; ++i) acc[i] = 0.f;

    int j = s0;
    for (; j + 2 <= s1; j += 2) {
        int sa = csr_src[j];
        int sb = csr_src[j + 1];
        uint4 ha = H8[(size_t)sa * LPG + lane];
        uint4 hb = H8[(size_t)sb * LPG + lane];
        fma8(dn, ha, acc);
        fma8(dn, hb, acc);
    }
    if (j < s1) {
        int sa = csr_src[j];
        uint4 ha = H8[(size_t)sa * LPG + lane];
        fma8(dn, ha, acc);
    }

    float4* O4 = reinterpret_cast<float4*>(Acc + (size_t)node * NOUT + lane * 8);
    float4 o0 = O4[0], o1 = O4[1];
    o0.x += acc[0]; o0.y += acc[1]; o0.z += acc[2]; o0.w += acc[3];
    o1.x += acc[4]; o1.y += acc[5]; o1.z += acc[6]; o1.w += acc[7];
    O4[0] = o0; O4[1] = o1;
}

// ---------------------------------------------------------------- launch
extern "C" void kernel_launch(void* const* d_in, const int* in_sizes, int n_in,
                              void* d_out, int out_size, void* d_ws, size_t ws_size,
                              hipStream_t stream) {
    const float* x  = (const float*)d_in[0];
    const int*   ei = (const int*)d_in[1];
    const float* W1 = (const float*)d_in[2];
    const float* b1 = (const float*)d_in[3];
    const float* W2 = (const float*)d_in[4];
    const float* b2 = (const float*)d_in[5];
    float* out = (float*)d_out;

    const int N = in_sizes[0] / 128;
    const int E = in_sizes[1] / 2;
    const int* src = ei;       // edge_index[0]
    const int* dst = ei + E;   // edge_index[1]
    const int NB = (N + BUCKET_NODES - 1) >> BUCKET_SHIFT;

    char* ws = (char*)d_ws;
    size_t off = 0;
    auto alloc = [&](size_t bytes) -> char* {
        char* p = ws + off;
        off += (bytes + 255) & ~size_t(255);
        return p;
    };
    int*            bucket_cursor = (int*)alloc((size_t)MAXNB * 4);
    int*            row_start     = (int*)alloc((size_t)N * 4);
    int*            row_end       = (int*)alloc((size_t)N * 4);
    float*          dinv          = (float*)alloc((size_t)N * 4);
    unsigned int*   rec           = (unsigned int*)alloc((size_t)NB * CAP * 4);
    int*            csr_src       = (int*)alloc((size_t)NB * CAP * 4);
    unsigned short* hs            = (unsigned short*)alloc((size_t)N * 128 * 2);
    float*          zp            = (float*)alloc((size_t)N * 128 * 4);
    (void)ws_size; (void)n_in; (void)out_size;

    constexpr int EPT = 8;
    const int bin_blocks = (E + 256 * EPT - 1) / (256 * EPT);

    hipLaunchKernelGGL(k_zero, dim3((NB + 255) / 256), dim3(256), 0, stream,
                       bucket_cursor, NB);
    hipLaunchKernelGGL((k_bin<EPT>), dim3(bin_blocks), dim3(256), 0, stream,
                       src, dst, bucket_cursor, rec, E, NB);
    hipLaunchKernelGGL(k_degcsr, dim3(NB), dim3(256), 0, stream,
                       bucket_cursor, rec, csr_src, row_start, row_end, dinv, N);

    // conv1: h = x@W1 ; zp = dinv^2*h + b1 ; zp += gathered msgs
    hipLaunchKernelGGL((k_gemm<128, false>), dim3((N + 31) / 32), dim3(256), 0, stream,
                       x, W1, b1, dinv, hs, zp, N);
    hipLaunchKernelGGL((k_gather<128>), dim3((N + 15) / 16), dim3(256), 0, stream,
                       row_start, row_end, csr_src, dinv, hs, zp, N);

    // conv2: h2 = relu(zp)@W2 ; out = dinv^2*h2 + b2 ; out += gathered msgs
    hipLaunchKernelGGL((k_gemm<64, true>), dim3((N + 63) / 64), dim3(256), 0, stream,
                       zp, W2, b2, dinv, hs, out, N);
    hipLaunchKernelGGL((k_gather<64>), dim3((N + 31) / 32), dim3(256), 0, stream,
                       row_start, row_end, csr_src, dinv, hs, out, N);
}

// Round 4
// 329.484 us; speedup vs baseline: 1.8359x; 1.1021x over previous
//
#include <hip/hip_runtime.h>

#define DEV_INLINE __device__ __forceinline__

static constexpr int KDIM = 128;
static constexpr int BUCKET_SHIFT = 8;           // 256 nodes per bucket
static constexpr int BUCKET_NODES = 1 << BUCKET_SHIFT;
static constexpr int CAP = 6144;                 // max edges per bucket (avg ~4096)
static constexpr int MAXNB = 512;                // max buckets supported

using s16x8 = __attribute__((ext_vector_type(8))) short;   // 8 bf16 (4 VGPR)
using f32x4 = __attribute__((ext_vector_type(4))) float;   // MFMA accumulator

// ---------------------------------------------------------------- helpers
DEV_INLINE float bf2f_lo(unsigned int u) {
    union { unsigned int u; float f; } c; c.u = u << 16; return c.f;
}
DEV_INLINE float bf2f_hi(unsigned int u) {
    union { unsigned int u; float f; } c; c.u = u & 0xFFFF0000u; return c.f;
}
DEV_INLINE unsigned int f2bf(float f) {      // round-to-nearest-even
    union { float f; unsigned int u; } c; c.f = f;
    return (c.u + 0x7FFFu + ((c.u >> 16) & 1u)) >> 16;
}

DEV_INLINE void fma8(float w, const uint4& h, float* acc) {
    acc[0] = fmaf(w, bf2f_lo(h.x), acc[0]);
    acc[1] = fmaf(w, bf2f_hi(h.x), acc[1]);
    acc[2] = fmaf(w, bf2f_lo(h.y), acc[2]);
    acc[3] = fmaf(w, bf2f_hi(h.y), acc[3]);
    acc[4] = fmaf(w, bf2f_lo(h.z), acc[4]);
    acc[5] = fmaf(w, bf2f_hi(h.z), acc[5]);
    acc[6] = fmaf(w, bf2f_lo(h.w), acc[6]);
    acc[7] = fmaf(w, bf2f_hi(h.w), acc[7]);
}

// ---------------------------------------------------------------- bucketed CSR build
__global__ void k_zero(int* __restrict__ bucket_cursor, int nb) {
    int i = blockIdx.x * 256 + threadIdx.x;
    if (i < nb) bucket_cursor[i] = 0;
}

template <int EPT>
__global__ __launch_bounds__(256) void k_bin(
    const int* __restrict__ src, const int* __restrict__ dst,
    int* __restrict__ bucket_cursor, unsigned int* __restrict__ rec,
    int E, int NB) {
    __shared__ int hist[MAXNB];
    __shared__ int base[MAXNB];
    const int t = threadIdx.x;
    for (int i = t; i < NB; i += 256) hist[i] = 0;
    __syncthreads();

    const int e0 = blockIdx.x * (256 * EPT);
    int d[EPT], s[EPT];
#pragma unroll
    for (int i = 0; i < EPT; ++i) {
        int e = e0 + i * 256 + t;
        d[i] = (e < E) ? dst[e] : -1;
        s[i] = (e < E) ? src[e] : 0;
    }
#pragma unroll
    for (int i = 0; i < EPT; ++i)
        if (d[i] >= 0) atomicAdd(&hist[d[i] >> BUCKET_SHIFT], 1);
    __syncthreads();

    for (int i = t; i < NB; i += 256) {
        int h = hist[i];
        base[i] = (h > 0) ? atomicAdd(&bucket_cursor[i], h) : 0;
        hist[i] = 0;   // reuse as local rank cursor
    }
    __syncthreads();

#pragma unroll
    for (int i = 0; i < EPT; ++i) {
        if (d[i] >= 0) {
            int b = d[i] >> BUCKET_SHIFT;
            int r = atomicAdd(&hist[b], 1);
            unsigned int p = (unsigned int)s[i] |
                             ((unsigned int)(d[i] & (BUCKET_NODES - 1)) << 24);
            rec[(size_t)b * CAP + base[b] + r] = p;
        }
    }
}

__global__ __launch_bounds__(256) void k_degcsr(
    const int* __restrict__ bucket_cursor, const unsigned int* __restrict__ rec,
    int* __restrict__ csr_src, int* __restrict__ row_start, int* __restrict__ row_end,
    float* __restrict__ dinv, int N) {
    __shared__ int cnt[BUCKET_NODES];
    __shared__ int rstart[BUCKET_NODES];
    __shared__ int sc[BUCKET_NODES];
    const int b = blockIdx.x;
    const int t = threadIdx.x;
    const int node0 = b << BUCKET_SHIFT;
    const int ne = bucket_cursor[b];
    cnt[t] = 0;
    __syncthreads();

    const unsigned int* r0 = rec + (size_t)b * CAP;
    for (int j = t; j < ne; j += 256) atomicAdd(&cnt[r0[j] >> 24], 1);
    __syncthreads();

    int v = cnt[t];
    sc[t] = v;
    __syncthreads();
    for (int off = 1; off < 256; off <<= 1) {
        int add = (t >= off) ? sc[t - off] : 0;
        __syncthreads();
        sc[t] += add;
        __syncthreads();
    }
    int rs = sc[t] - v;  // exclusive
    rstart[t] = rs;
    if (node0 + t < N) {
        row_start[node0 + t] = b * CAP + rs;
        row_end[node0 + t]   = b * CAP + rs + v;
        dinv[node0 + t] = rsqrtf((float)v + 1.0f);  // +1 self-loop
    }
    cnt[t] = 0;  // reuse as rank cursor
    __syncthreads();

    for (int j = t; j < ne; j += 256) {
        unsigned int p = r0[j];
        int loc = p >> 24;
        int rk = atomicAdd(&cnt[loc], 1);
        csr_src[(size_t)b * CAP + rstart[loc] + rk] = (int)(p & 0x00FFFFFFu);
    }
}

// ---------------------------------------------------------------- W pre-swizzle into MFMA B-fragment order
// Wf layout: frag f = (variant*4 + kstep)*CT + ct ; ushort offset f*512 + lane*8 + j
// value = W[k][n], k = kstep*32 + (lane>>4)*8 + j, n = ct*16 + (lane&15)
// variant 0 = bf16(W) ; variant 1 = bf16(W - bf16(W))
__global__ void k_wprep(const float* __restrict__ W, unsigned short* __restrict__ Wf,
                        int NOUT) {
    const int tid = blockIdx.x * 256 + threadIdx.x;
    const int CT = NOUT >> 4;
    const int total = 8 * CT * 64;   // 2 variants * 4 ksteps * CT * 64 lanes
    if (tid >= total) return;
    const int lane = tid & 63;
    const int f = tid >> 6;
    const int v = f / (4 * CT);
    const int r = f - v * 4 * CT;
    const int s = r / CT;
    const int ct = r - s * CT;
    const int k0 = s * 32 + ((lane >> 4) << 3);
    const int n = (ct << 4) + (lane & 15);
    unsigned int pk[4];
#pragma unroll
    for (int jp = 0; jp < 4; ++jp) {
        unsigned int h2[2];
#pragma unroll
        for (int e = 0; e < 2; ++e) {
            int j = jp * 2 + e;
            float w = W[(size_t)(k0 + j) * NOUT + n];
            unsigned int hb = f2bf(w);
            if (v) hb = f2bf(w - bf2f_lo(hb));
            h2[e] = hb;
        }
        pk[jp] = h2[0] | (h2[1] << 16);
    }
    reinterpret_cast<uint4*>(Wf)[tid] = make_uint4(pk[0], pk[1], pk[2], pk[3]);
}

// ---------------------------------------------------------------- MFMA GEMM  H = act(A) @ W
// 3-term bf16 split (hi*hi + lo*hi + hi*lo) == fp32 accuracy to ~2^-18.
// Per wave: 16 rows x NOUT cols. A read direct from global, converted in-reg.
// Epilogue: Hs[row] = bf16(dinv*acc) ; OutInit[row] = dinv^2*acc + bias.
template <int NOUT, bool RELU_IN>
__global__ __launch_bounds__(256, 2) void k_mgemm(
    const float* __restrict__ A, const unsigned short* __restrict__ Wf,
    const float* __restrict__ bias, const float* __restrict__ dinv,
    unsigned short* __restrict__ Hs, float* __restrict__ OutInit, int N) {
    constexpr int CT = NOUT / 16;
    constexpr int U4 = CT * 512;         // uint4 count = 2*4*CT*64*8/8
    __shared__ uint4 WfL[U4];            // 64 KB (NOUT=128) / 32 KB (NOUT=64)
    for (int i = threadIdx.x; i < U4; i += 256)
        WfL[i] = reinterpret_cast<const uint4*>(Wf)[i];
    __syncthreads();

    const int lane = threadIdx.x & 63;
    const int kg = lane >> 4;            // 0..3
    const int lm = lane & 15;
    const int r0 = blockIdx.x * 64 + (threadIdx.x >> 6) * 16;
    const int arow = r0 + lm;

    // load + split A rows (lane holds A[arow][kstep*32 + kg*8 .. +7])
    s16x8 ah[4], al[4];
    const float4* A4 = reinterpret_cast<const float4*>(A);
#pragma unroll
    for (int s = 0; s < 4; ++s) {
        float4 p0 = make_float4(0.f, 0.f, 0.f, 0.f);
        float4 p1 = p0;
        if (arow < N) {
            p0 = A4[(size_t)arow * 32 + s * 8 + kg * 2];
            p1 = A4[(size_t)arow * 32 + s * 8 + kg * 2 + 1];
        }
        float vf[8] = {p0.x, p0.y, p0.z, p0.w, p1.x, p1.y, p1.z, p1.w};
#pragma unroll
        for (int j = 0; j < 8; ++j) {
            float w = RELU_IN ? fmaxf(vf[j], 0.f) : vf[j];
            unsigned int hb = f2bf(w);
            ah[s][j] = (short)hb;
            al[s][j] = (short)f2bf(w - bf2f_lo(hb));
        }
    }

    float dv[4];
#pragma unroll
    for (int q = 0; q < 4; ++q) {
        int orow = r0 + kg * 4 + q;
        dv[q] = (orow < N) ? dinv[orow] : 0.f;
    }

    const unsigned short* LW = reinterpret_cast<const unsigned short*>(WfL);
#pragma unroll
    for (int ct = 0; ct < CT; ++ct) {
        f32x4 acc = {0.f, 0.f, 0.f, 0.f};
#pragma unroll
        for (int s = 0; s < 4; ++s) {
            s16x8 bh = *reinterpret_cast<const s16x8*>(LW + ((size_t)(s * CT + ct)) * 512 + lane * 8);
            s16x8 bl = *reinterpret_cast<const s16x8*>(LW + ((size_t)((4 + s) * CT + ct)) * 512 + lane * 8);
            acc = __builtin_amdgcn_mfma_f32_16x16x32_bf16(ah[s], bh, acc, 0, 0, 0);
            acc = __builtin_amdgcn_mfma_f32_16x16x32_bf16(al[s], bh, acc, 0, 0, 0);
            acc = __builtin_amdgcn_mfma_f32_16x16x32_bf16(ah[s], bl, acc, 0, 0, 0);
        }
        const int col = ct * 16 + lm;
        const float bb = bias[col];
#pragma unroll
        for (int q = 0; q < 4; ++q) {
            int orow = r0 + kg * 4 + q;
            if (orow < N) {
                float h = acc[q];
                float di = dv[q];
                Hs[(size_t)orow * NOUT + col] = (unsigned short)f2bf(di * h);
                OutInit[(size_t)orow * NOUT + col] = fmaf(di * di, h, bb);
            }
        }
    }
}

// ---------------------------------------------------------------- CSR gather-aggregate
// Acc[node] += dinv[node] * sum_j Hs[src_j]     (Hs pre-scaled by dinv[src])
template <int NOUT>
__global__ void k_gather(const int* __restrict__ row_start, const int* __restrict__ row_end,
                         const int* __restrict__ csr_src,
                         const float* __restrict__ dinv,
                         const unsigned short* __restrict__ Hs,
                         float* __restrict__ Acc, int N) {
    constexpr int LPG = NOUT / 8;
    const int lane = threadIdx.x % LPG;
    const int node = blockIdx.x * (256 / LPG) + threadIdx.x / LPG;
    if (node >= N) return;
    const int s0 = row_start[node];
    const int s1 = row_end[node];
    if (s0 == s1) return;
    const float dn = dinv[node];
    const uint4* H8 = reinterpret_cast<const uint4*>(Hs);
    float acc[8];
#pragma unroll
    for (int i = 0; i < 8; ++i) acc[i] = 0.f;

    int j = s0;
    for (; j + 2 <= s1; j += 2) {
        int sa = csr_src[j];
        int sb = csr_src[j + 1];
        uint4 ha = H8[(size_t)sa * LPG + lane];
        uint4 hb = H8[(size_t)sb * LPG + lane];
        fma8(dn, ha, acc);
        fma8(dn, hb, acc);
    }
    if (j < s1) {
        int sa = csr_src[j];
        uint4 ha = H8[(size_t)sa * LPG + lane];
        fma8(dn, ha, acc);
    }

    float4* O4 = reinterpret_cast<float4*>(Acc + (size_t)node * NOUT + lane * 8);
    float4 o0 = O4[0], o1 = O4[1];
    o0.x += acc[0]; o0.y += acc[1]; o0.z += acc[2]; o0.w += acc[3];
    o1.x += acc[4]; o1.y += acc[5]; o1.z += acc[6]; o1.w += acc[7];
    O4[0] = o0; O4[1] = o1;
}

// ---------------------------------------------------------------- launch
extern "C" void kernel_launch(void* const* d_in, const int* in_sizes, int n_in,
                              void* d_out, int out_size, void* d_ws, size_t ws_size,
                              hipStream_t stream) {
    const float* x  = (const float*)d_in[0];
    const int*   ei = (const int*)d_in[1];
    const float* W1 = (const float*)d_in[2];
    const float* b1 = (const float*)d_in[3];
    const float* W2 = (const float*)d_in[4];
    const float* b2 = (const float*)d_in[5];
    float* out = (float*)d_out;

    const int N = in_sizes[0] / 128;
    const int E = in_sizes[1] / 2;
    const int* src = ei;       // edge_index[0]
    const int* dst = ei + E;   // edge_index[1]
    const int NB = (N + BUCKET_NODES - 1) >> BUCKET_SHIFT;

    char* ws = (char*)d_ws;
    size_t off = 0;
    auto alloc = [&](size_t bytes) -> char* {
        char* p = ws + off;
        off += (bytes + 255) & ~size_t(255);
        return p;
    };
    int*            bucket_cursor = (int*)alloc((size_t)MAXNB * 4);
    int*            row_start     = (int*)alloc((size_t)N * 4);
    int*            row_end       = (int*)alloc((size_t)N * 4);
    float*          dinv          = (float*)alloc((size_t)N * 4);
    unsigned int*   rec           = (unsigned int*)alloc((size_t)NB * CAP * 4);
    int*            csr_src       = (int*)alloc((size_t)NB * CAP * 4);
    unsigned short* hs            = (unsigned short*)alloc((size_t)N * 128 * 2);
    float*          zp            = (float*)alloc((size_t)N * 128 * 4);
    unsigned short* wf1           = (unsigned short*)alloc(128 * 128 * 2 * 2);  // 64 KB
    unsigned short* wf2           = (unsigned short*)alloc(128 * 64 * 2 * 2);   // 32 KB
    (void)ws_size; (void)n_in; (void)out_size;

    constexpr int EPT = 8;
    const int bin_blocks = (E + 256 * EPT - 1) / (256 * EPT);

    hipLaunchKernelGGL(k_zero, dim3((NB + 255) / 256), dim3(256), 0, stream,
                       bucket_cursor, NB);
    hipLaunchKernelGGL(k_wprep, dim3(16), dim3(256), 0, stream, W1, wf1, 128);
    hipLaunchKernelGGL(k_wprep, dim3(8), dim3(256), 0, stream, W2, wf2, 64);
    hipLaunchKernelGGL((k_bin<EPT>), dim3(bin_blocks), dim3(256), 0, stream,
                       src, dst, bucket_cursor, rec, E, NB);
    hipLaunchKernelGGL(k_degcsr, dim3(NB), dim3(256), 0, stream,
                       bucket_cursor, rec, csr_src, row_start, row_end, dinv, N);

    // conv1: h = x@W1 ; zp = dinv^2*h + b1 ; zp += gathered msgs
    hipLaunchKernelGGL((k_mgemm<128, false>), dim3((N + 63) / 64), dim3(256), 0, stream,
                       x, wf1, b1, dinv, hs, zp, N);
    hipLaunchKernelGGL((k_gather<128>), dim3((N + 15) / 16), dim3(256), 0, stream,
                       row_start, row_end, csr_src, dinv, hs, zp, N);

    // conv2: h2 = relu(zp)@W2 ; out = dinv^2*h2 + b2 ; out += gathered msgs
    hipLaunchKernelGGL((k_mgemm<64, true>), dim3((N + 63) / 64), dim3(256), 0, stream,
                       zp, wf2, b2, dinv, hs, out, N);
    hipLaunchKernelGGL((k_gather<64>), dim3((N + 31) / 32), dim3(256), 0, stream,
                       row_start, row_end, csr_src, dinv, hs, out, N);
}